// Round 1
// 203.394 us; speedup vs baseline: 1.1777x; 1.1777x over previous
//
#include <hip/hip_runtime.h>
#include <hip/hip_fp16.h>

// Fused Conv3d(3->16, 3x3x3, VALID) + bias + channel softmax + maxpool(4,4,4)/4.
// x: [512,3,16,32,32] f32, w: [16,3,3,3,3] f32, b: [16] f32 -> out [512,16,3,7,7] f32
//
// R11: same MFMA implicit GEMM as R10 (mfma_f32_16x16x32_f16, A=frag-ready
// weights, B gathered from LDS with parity-duplicated copy), with two fixes:
//  (a) LDS bank-conflict elimination: w-row stride padded 16->17 ints so tap
//      rows walk 17r mod 32 banks (was {0,16}); dup copy placed at +1837 ints
//      (odd, ==13 mod 32) so odd-parity lanes sit 13 banks from even partners.
//      R10 had every lane pair + all 4 k-groups on the same 8 banks (~8-way).
//  (b) 256-thread blocks: 4 waves share one staged tile, wave w owns dd=w
//      (7 N-tiles/wave). pool buffer unioned into the tile LDS after a barrier
//      -> 14692 B/block for 4 waves (was 17408 B for 2) -> occupancy up.

typedef _Float16 half8 __attribute__((ext_vector_type(8)));
typedef float f32x4 __attribute__((ext_vector_type(4)));
union H8 { int4 i; half8 h; };

// Build frag-ready weights: wsA[v][lane] = 8 halves A[c=lane&15][k=32v+8(lane>>4)+j].
// tap group G = k>>2 = 8v+2g+(j>>2), kw = k&3; zero for G>=27 or kw==3.
__global__ void wtrans(const float* __restrict__ w, int4* __restrict__ wsA) {
  int t = threadIdx.x;            // 256 threads: v = t>>6, lane = t&63
  int v = t >> 6, l = t & 63;
  int c = l & 15, g = l >> 4;
  unsigned hh[8];
  for (int j = 0; j < 8; ++j) {
    int G = 8 * v + 2 * g + (j >> 2);
    int kw = j & 3;
    float val = (G < 27 && kw < 3) ? w[c * 81 + G * 3 + kw] : 0.0f;
    __half h = __float2half(val);
    hh[j] = (unsigned)__half_as_ushort(h);
  }
  int4 o;
  o.x = (int)(hh[0] | (hh[1] << 16));
  o.y = (int)(hh[2] | (hh[3] << 16));
  o.z = (int)(hh[4] | (hh[5] << 16));
  o.w = (int)(hh[6] | (hh[7] << 16));
  wsA[v * 64 + l] = o;
}

__global__ __launch_bounds__(256, 6) void conv_sm_pool(
    const float* __restrict__ x, const int4* __restrict__ wsA,
    const float* __restrict__ b, float* __restrict__ out) {
  // x tile as half pairs: 108 rows (cin*36+ld*6+lh) x 17 ints (16 data + 1 pad).
  // xs = lds[0..1835], spare lds[1836], dup = lds[1837..3672].
  // dup[i] = halves(2i+1, 2i+2) of the xs half-stream (per padded row).
  // After the main loop, lds is reused as pool buffer [dd*4+dh][pw][c] (16*7*16 f32).
  __shared__ int lds[3673];
  int* xs = lds;
  int* dup = lds + 1837;

  const int tid = threadIdx.x;
  const int blk = blockIdx.x;
  const int n = blk / 21, rr = blk % 21, pd = rr / 7, ph = rr % 7;

  // ---- stage x tile as fp16 pairs (rows padded to 17 ints) ----
  const float* xb = x + ((size_t)n * 3 * 16 * 32 * 32)
                  + (size_t)(4 * pd) * 1024 + (size_t)(4 * ph) * 32;
  for (int i = tid; i < 1728; i += 256) {
    int col = i & 15;
    int row = i >> 4;           // cin*36 + ld*6 + lh
    int lh = row % 6, t2 = row / 6, ld = t2 % 6, cin = t2 / 6;
    float2 v = *reinterpret_cast<const float2*>(
        &xb[((cin * 16 + ld) * 32 + lh) * 32 + col * 2]);
    __half2 h2 = __float22half2_rn(v);
    xs[row * 17 + col] = *reinterpret_cast<int*>(&h2);
  }
  __syncthreads();
  // ---- shifted duplicate for odd-parity lanes (pad ints produce garbage
  //      that is never read: in-row int reads stop at col 14) ----
  for (int i = tid; i < 1836; i += 256)
    dup[i] = (int)(((unsigned)xs[i] >> 16) | ((unsigned)xs[i + 1] << 16));
  __syncthreads();

  const int lane = tid & 63;
  const int dd = tid >> 6;            // wave = one dd slice (0..3)
  const int l15 = lane & 15, g = lane >> 4;
  const int par = l15 & 1;
  const int* bas = par ? dup : xs;

  // A-frags (weights), held in regs
  H8 wa[4];
#pragma unroll
  for (int v = 0; v < 4; ++v) wa[v].i = wsA[v * 64 + lane];

  // tap-group int-offsets per window: row (cin,kd,kh) strides 612/102/17 ints
  int TH0[4], TH1[4];
#pragma unroll
  for (int v = 0; v < 4; ++v) {
    int G0 = 8 * v + 2 * g, G1 = G0 + 1;
    if (G0 > 26) G0 = 26;
    if (G1 > 26) G1 = 26;
    int c0 = G0 / 9, r0 = G0 % 9, c1 = G1 / 9, r1 = G1 % 9;
    TH0[v] = c0 * 612 + (r0 / 3) * 102 + (r0 % 3) * 17;
    TH1[v] = c1 * 612 + (r1 / 3) * 102 + (r1 % 3) * 17;
  }

  // position int-offsets per N-tile: P(halves) = dd*204 + dh*34 + wp
  int PH[7];
#pragma unroll
  for (int tl = 0; tl < 7; ++tl) {
    int rem = tl * 16;                    // 0,16,32,...,96 (compile-time)
    int dh0 = rem / 28, rem28 = rem % 28; // rem28 even -> wp parity == l15 parity
    int bump = (rem28 + l15) >= 28 ? 1 : 0;
    int P = dd * 204 + (dh0 + bump) * 34 + (rem28 + l15 - 28 * bump);
    PH[tl] = (P - par) >> 1;
  }

  // acc init with bias (row = channel = 4g+q)
  f32x4 acc[7];
  float4 b4 = *reinterpret_cast<const float4*>(b + 4 * g);
  f32x4 binit;
  binit[0] = b4.x; binit[1] = b4.y; binit[2] = b4.z; binit[3] = b4.w;
#pragma unroll
  for (int tl = 0; tl < 7; ++tl) acc[tl] = binit;

  // ---- main: 4 K-windows x 7 N-tiles ----
#pragma unroll
  for (int v = 0; v < 4; ++v) {
#pragma unroll
    for (int tl = 0; tl < 7; ++tl) {
      int o0 = PH[tl] + TH0[v];
      int o1 = PH[tl] + TH1[v];
      H8 bf;
      bf.i.x = bas[o0];
      bf.i.y = bas[o0 + 1];
      bf.i.z = bas[o1];
      bf.i.w = bas[o1 + 1];
      acc[tl] = __builtin_amdgcn_mfma_f32_16x16x32_f16(wa[v].h, bf.h, acc[tl], 0, 0, 0);
    }
  }

  // ---- epilogue: softmax over channels (cross lane-group), pool ----
  __syncthreads();      // all LDS tile reads done; reuse lds as pool buffer
  float* pool2 = reinterpret_cast<float*>(lds);   // [dd*4+dh][pw][c]

#pragma unroll
  for (int tl = 0; tl < 7; ++tl) {
    float e[4];
#pragma unroll
    for (int q = 0; q < 4; ++q) e[q] = __expf(acc[tl][q]);
    float s = (e[0] + e[1]) + (e[2] + e[3]);
    s += __shfl_xor(s, 16, 64);
    s += __shfl_xor(s, 32, 64);
    float rs = __builtin_amdgcn_rcpf(s);
    float pm[4];
#pragma unroll
    for (int q = 0; q < 4; ++q) pm[q] = e[q] * rs;
    // wp-quad reduce (l15 quads are exact wp quads; quads never straddle dh)
#pragma unroll
    for (int q = 0; q < 4; ++q) {
      pm[q] = fmaxf(pm[q], __shfl_xor(pm[q], 1, 64));
      pm[q] = fmaxf(pm[q], __shfl_xor(pm[q], 2, 64));
    }
    if ((l15 & 3) == 0) {
      int rem = tl * 16;
      int dh0 = rem / 28, rem28 = rem % 28;
      int bump = (rem28 + l15) >= 28 ? 1 : 0;
      int dh = dh0 + bump;
      int pw = (rem28 + l15 - 28 * bump) >> 2;
      float4 val = {pm[0], pm[1], pm[2], pm[3]};
      *reinterpret_cast<float4*>(&pool2[(((dd * 4 + dh) * 7 + pw) << 4) + 4 * g]) = val;
    }
  }
  __syncthreads();

  if (tid < 112) {
    int c = tid / 7, pw = tid % 7;
    float m = pool2[(pw << 4) + c];
#pragma unroll
    for (int s2 = 1; s2 < 16; ++s2)
      m = fmaxf(m, pool2[((s2 * 7 + pw) << 4) + c]);
    out[(((size_t)n * 16 + c) * 3 + pd) * 49 + (size_t)ph * 7 + pw] = m;
  }
}

extern "C" void kernel_launch(void* const* d_in, const int* in_sizes, int n_in,
                              void* d_out, int out_size, void* d_ws, size_t ws_size,
                              hipStream_t stream) {
  const float* x = (const float*)d_in[0];
  const float* w = (const float*)d_in[1];
  const float* b = (const float*)d_in[2];
  float* out = (float*)d_out;
  int4* wsA = (int4*)d_ws;   // 4 windows * 64 lanes * 16 B = 4096 B
  (void)in_sizes; (void)n_in; (void)out_size; (void)ws_size;
  hipLaunchKernelGGL(wtrans, dim3(1), dim3(256), 0, stream, w, wsA);
  hipLaunchKernelGGL(conv_sm_pool, dim3(512 * 3 * 7), dim3(256), 0, stream,
                     x, wsA, b, out);
}

// Round 2
// 200.569 us; speedup vs baseline: 1.1943x; 1.0141x over previous
//
#include <hip/hip_runtime.h>
#include <hip/hip_fp16.h>

// Fused Conv3d(3->16, 3x3x3, VALID) + bias + channel softmax + maxpool(4,4,4)/4.
// x: [512,3,16,32,32] f32, w: [16,3,3,3,3] f32, b: [16] f32 -> out [512,16,3,7,7] f32
//
// R12: K=16 MFMA (mfma_f32_16x16x16_f16) so each lane's B-frag is ONE contiguous
// 4-half tap-row group -> ONE aligned ds_read_b64 per MFMA (was 4x ds_read_b32
// per K=32 MFMA). LDS holds 4 shift-copies of the tile half-stream (shift 0..3
// halves); copy c = Q&3 serves half-window Q..Q+3 at even int index (Q-c)/2.
// Copy stride 1736 ints == 8 mod 32 + unpadded 16-int rows -> each 16-lane group
// covers all 32 banks exactly once -> gather is conflict-free (uniform 4/bank).
// Staging: copy0 via float4+cvt_pk+ds_write_b64; copies 1-3 built in one b128
// pass (copy2 = copy0 shifted 1 int; copy1/3 = 16-bit funnel shifts).
// 256 threads, wave = one dd slice; softmax/pool epilogue unchanged from R11.

typedef _Float16 half4 __attribute__((ext_vector_type(4)));
typedef float f32x4 __attribute__((ext_vector_type(4)));
union H4 { int2 i; half4 h; };

// Frag-ready weights for K=16: wsA[v][lane] = 4 halves A[c=lane&15][k=16v+4g+j],
// tap G = 4v+g, kw = j; zero for G>=27 or kw==3.
__global__ void wtrans(const float* __restrict__ w, int2* __restrict__ wsA) {
  int t = threadIdx.x;            // 448 threads: v = t>>6, lane = t&63
  if (t >= 448) return;
  int v = t >> 6, l = t & 63;
  int c = l & 15, g = l >> 4;
  int G = 4 * v + g;
  unsigned hh[4];
  for (int j = 0; j < 4; ++j) {
    float val = (G < 27 && j < 3) ? w[c * 81 + G * 3 + j] : 0.0f;
    __half h = __float2half(val);
    hh[j] = (unsigned)__half_as_ushort(h);
  }
  int2 o;
  o.x = (int)(hh[0] | (hh[1] << 16));
  o.y = (int)(hh[2] | (hh[3] << 16));
  wsA[v * 64 + l] = o;
}

__global__ __launch_bounds__(256, 5) void conv_sm_pool(
    const float* __restrict__ x, const int2* __restrict__ wsA,
    const float* __restrict__ b, float* __restrict__ out) {
  // 4 shifted copies of the 3456-half tile stream, copy stride 1736 ints
  // (1736 mod 32 = 8; copies base at 0,1736,3472,5208). Rows unpadded:
  // row (cin,ld,lh) = 32 halves = 16 ints. After main loop, reused as pool buf.
  __shared__ int lds[6944];

  const int tid = threadIdx.x;
  const int blk = blockIdx.x;
  const int n = blk / 21, rr = blk % 21, pd = rr / 7, ph = rr % 7;

  const float* xb = x + ((size_t)n * 3 * 16 * 32 * 32)
                  + (size_t)(4 * pd) * 1024 + (size_t)(4 * ph) * 32;

  // ---- stage copy0: 864 int-pairs (u -> halves 4u..4u+3) ----
  for (int u = tid; u < 864; u += 256) {
    int r = u >> 3, c4 = (u & 7) * 4;
    int lh = r % 6, t2 = r / 6, ld = t2 % 6, cin = t2 / 6;
    float4 v4 = *reinterpret_cast<const float4*>(
        &xb[((cin * 16 + ld) * 32 + lh) * 32 + c4]);
    __half2 h01 = __float22half2_rn(make_float2(v4.x, v4.y));
    __half2 h23 = __float22half2_rn(make_float2(v4.z, v4.w));
    int2 o;
    o.x = *reinterpret_cast<int*>(&h01);
    o.y = *reinterpret_cast<int*>(&h23);
    *reinterpret_cast<int2*>(&lds[2 * u]) = o;
  }
  __syncthreads();

  // ---- build copies 1..3 (shift 1,2,3 halves). chunk = 8 ints/thread.
  //      reads lds[1728,1729] (unwritten slack, in-bounds); the garbage only
  //      lands in tail ints that are provably never read (max Q+3 = 3454). ----
  if (tid < 216) {
    int i0 = 8 * tid;
    int4 A = *reinterpret_cast<const int4*>(&lds[i0]);
    int4 B = *reinterpret_cast<const int4*>(&lds[i0 + 4]);
    int2 C = *reinterpret_cast<const int2*>(&lds[i0 + 8]);
    int c0[10] = {A.x, A.y, A.z, A.w, B.x, B.y, B.z, B.w, C.x, C.y};
    int a[9];
#pragma unroll
    for (int i = 0; i < 9; ++i)
      a[i] = (int)(((unsigned)c0[i] >> 16) | ((unsigned)c0[i + 1] << 16));
    int4 w0; w0.x = a[0]; w0.y = a[1]; w0.z = a[2]; w0.w = a[3];
    int4 w1; w1.x = a[4]; w1.y = a[5]; w1.z = a[6]; w1.w = a[7];
    *reinterpret_cast<int4*>(&lds[1736 + i0])     = w0;
    *reinterpret_cast<int4*>(&lds[1736 + i0 + 4]) = w1;
    int4 w2; w2.x = c0[1]; w2.y = c0[2]; w2.z = c0[3]; w2.w = c0[4];
    int4 w3; w3.x = c0[5]; w3.y = c0[6]; w3.z = c0[7]; w3.w = c0[8];
    *reinterpret_cast<int4*>(&lds[3472 + i0])     = w2;
    *reinterpret_cast<int4*>(&lds[3472 + i0 + 4]) = w3;
    int4 w4; w4.x = a[1]; w4.y = a[2]; w4.z = a[3]; w4.w = a[4];
    int4 w5; w5.x = a[5]; w5.y = a[6]; w5.z = a[7]; w5.w = a[8];
    *reinterpret_cast<int4*>(&lds[5208 + i0])     = w4;
    *reinterpret_cast<int4*>(&lds[5208 + i0 + 4]) = w5;
  }
  __syncthreads();

  const int lane = tid & 63;
  const int dd = tid >> 6;            // wave = one dd slice (0..3)
  const int l15 = lane & 15, g = lane >> 4;

  // A-frags (weights), 7 K-windows x 2 VGPRs
  H4 wa[7];
#pragma unroll
  for (int v = 0; v < 7; ++v) wa[v].i = wsA[v * 64 + lane];

  // tap-group int offsets: T = cin*576 + kd*96 + kh*16 for G = 4v+g (clamped)
  int tvi[7];
#pragma unroll
  for (int v = 0; v < 7; ++v) {
    int G = 4 * v + g;
    if (G > 26) G = 26;
    int cin = G / 9, r = G % 9;
    tvi[v] = cin * 576 + (r / 3) * 96 + (r % 3) * 16;
  }

  // position bases: P = dd*192 + dh*32 + wp (halves);
  // pbi = ((P&~3)>>1) + 1736*(P&3)  (copy select is linear in P&3)
  int pbi[7];
#pragma unroll
  for (int tl = 0; tl < 7; ++tl) {
    int rem = tl * 16;
    int dh0 = rem / 28, rem28 = rem % 28;
    int bump = (rem28 + l15) >= 28 ? 1 : 0;
    int P = dd * 192 + (dh0 + bump) * 32 + (rem28 + l15 - 28 * bump);
    pbi[tl] = ((P & ~3) >> 1) + 1736 * (P & 3);
  }

  // acc init with bias (row = channel = 4g+q)
  f32x4 acc[7];
  float4 b4 = *reinterpret_cast<const float4*>(b + 4 * g);
  f32x4 binit;
  binit[0] = b4.x; binit[1] = b4.y; binit[2] = b4.z; binit[3] = b4.w;
#pragma unroll
  for (int tl = 0; tl < 7; ++tl) acc[tl] = binit;

  // ---- main: 7 K-windows x 7 N-tiles, 1 ds_read_b64 + 1 MFMA each ----
#pragma unroll
  for (int v = 0; v < 7; ++v) {
#pragma unroll
    for (int tl = 0; tl < 7; ++tl) {
      H4 bf;
      bf.i = *reinterpret_cast<const int2*>(&lds[pbi[tl] + tvi[v]]);
      acc[tl] = __builtin_amdgcn_mfma_f32_16x16x16f16(wa[v].h, bf.h, acc[tl], 0, 0, 0);
    }
  }

  // ---- epilogue: softmax over channels (cross lane-group), pool ----
  __syncthreads();      // all LDS tile reads done; reuse lds as pool buffer
  float* pool2 = reinterpret_cast<float*>(lds);   // [dd*4+dh][pw][c]

#pragma unroll
  for (int tl = 0; tl < 7; ++tl) {
    float e[4];
#pragma unroll
    for (int q = 0; q < 4; ++q) e[q] = __expf(acc[tl][q]);
    float s = (e[0] + e[1]) + (e[2] + e[3]);
    s += __shfl_xor(s, 16, 64);
    s += __shfl_xor(s, 32, 64);
    float rs = __builtin_amdgcn_rcpf(s);
    float pm[4];
#pragma unroll
    for (int q = 0; q < 4; ++q) pm[q] = e[q] * rs;
    // wp-quad reduce (l15 quads are exact wp quads; quads never straddle dh)
#pragma unroll
    for (int q = 0; q < 4; ++q) {
      pm[q] = fmaxf(pm[q], __shfl_xor(pm[q], 1, 64));
      pm[q] = fmaxf(pm[q], __shfl_xor(pm[q], 2, 64));
    }
    if ((l15 & 3) == 0) {
      int rem = tl * 16;
      int dh0 = rem / 28, rem28 = rem % 28;
      int bump = (rem28 + l15) >= 28 ? 1 : 0;
      int dh = dh0 + bump;
      int pw = (rem28 + l15 - 28 * bump) >> 2;
      float4 val = {pm[0], pm[1], pm[2], pm[3]};
      *reinterpret_cast<float4*>(&pool2[(((dd * 4 + dh) * 7 + pw) << 4) + 4 * g]) = val;
    }
  }
  __syncthreads();

  if (tid < 112) {
    int c = tid / 7, pw = tid % 7;
    float m = pool2[(pw << 4) + c];
#pragma unroll
    for (int s2 = 1; s2 < 16; ++s2)
      m = fmaxf(m, pool2[((s2 * 7 + pw) << 4) + c]);
    out[(((size_t)n * 16 + c) * 3 + pd) * 49 + (size_t)ph * 7 + pw] = m;
  }
}

extern "C" void kernel_launch(void* const* d_in, const int* in_sizes, int n_in,
                              void* d_out, int out_size, void* d_ws, size_t ws_size,
                              hipStream_t stream) {
  const float* x = (const float*)d_in[0];
  const float* w = (const float*)d_in[1];
  const float* b = (const float*)d_in[2];
  float* out = (float*)d_out;
  int2* wsA = (int2*)d_ws;   // 7 windows * 64 lanes * 8 B = 3584 B
  (void)in_sizes; (void)n_in; (void)out_size; (void)ws_size;
  hipLaunchKernelGGL(wtrans, dim3(1), dim3(448), 0, stream, w, wsA);
  hipLaunchKernelGGL(conv_sm_pool, dim3(512 * 3 * 7), dim3(256), 0, stream,
                     x, wsA, b, out);
}

// Round 3
// 199.392 us; speedup vs baseline: 1.2014x; 1.0059x over previous
//
#include <hip/hip_runtime.h>
#include <hip/hip_fp16.h>

// Fused Conv3d(3->16, 3x3x3, VALID) + bias + channel softmax + maxpool(4,4,4)/4.
// x: [512,3,16,32,32] f32, w: [16,3,3,3,3] f32, b: [16] f32 -> out [512,16,3,7,7] f32
//
// R13: R12 layout (K=16 MFMA, 4 shift-copies, 1 ds_read_b64 per MFMA) was shown
// to be latency-bound, not LDS-throughput-bound (VGPR=44 -> ~2 loads in flight,
// ~50-120cy exposed per gather; no pipe >55% busy). This round:
//  (a) explicit double-buffered pipeline: issue all 7 ds_read_b64 of K-window
//      v+1 while the 7 MFMAs of window v run (static bfA/bfB names, unrolled).
//  (b) hoist weight-frag global loads + pbi/tvi/bias setup above the staging
//      barriers so setup latency hides under the x-tile staging.
//  (c) __launch_bounds__(256,4): allow ~100 VGPR for the in-flight frags.
// Bank note: gather is conflict-free in b64 pair-units (p = (P/4 + 4q) mod 16
// is a perfect 16-spread per lane-group; T/2 mod 16 in {0,8} maps the set onto
// itself). Counter residue comes from dh-bump tiles (2-way, free per m136).

typedef _Float16 half4 __attribute__((ext_vector_type(4)));
typedef float f32x4 __attribute__((ext_vector_type(4)));
union H4 { int2 i; half4 h; };

// Frag-ready weights for K=16: wsA[v][lane] = 4 halves A[c=lane&15][k=16v+4g+j],
// tap G = 4v+g, kw = j; zero for G>=27 or kw==3.
__global__ void wtrans(const float* __restrict__ w, int2* __restrict__ wsA) {
  int t = threadIdx.x;            // 448 threads: v = t>>6, lane = t&63
  if (t >= 448) return;
  int v = t >> 6, l = t & 63;
  int c = l & 15, g = l >> 4;
  int G = 4 * v + g;
  unsigned hh[4];
  for (int j = 0; j < 4; ++j) {
    float val = (G < 27 && j < 3) ? w[c * 81 + G * 3 + j] : 0.0f;
    __half h = __float2half(val);
    hh[j] = (unsigned)__half_as_ushort(h);
  }
  int2 o;
  o.x = (int)(hh[0] | (hh[1] << 16));
  o.y = (int)(hh[2] | (hh[3] << 16));
  wsA[v * 64 + l] = o;
}

__global__ __launch_bounds__(256, 4) void conv_sm_pool(
    const float* __restrict__ x, const int2* __restrict__ wsA,
    const float* __restrict__ b, float* __restrict__ out) {
  // 4 shifted copies of the 3456-half tile stream, copy stride 1736 ints
  // (copies base at 0,1736,3472,5208). Rows unpadded: row (cin,ld,lh) =
  // 32 halves = 16 ints. After the main loop, reused as pool buffer.
  __shared__ int lds[6944];

  const int tid = threadIdx.x;
  const int blk = blockIdx.x;
  const int n = blk / 21, rr = blk % 21, pd = rr / 7, ph = rr % 7;

  const int lane = tid & 63;
  const int dd = tid >> 6;            // wave = one dd slice (0..3)
  const int l15 = lane & 15, g = lane >> 4;

  // ---- setup hoisted above staging: global loads + index math ----
  H4 wa[7];
#pragma unroll
  for (int v = 0; v < 7; ++v) wa[v].i = wsA[v * 64 + lane];

  float4 b4 = *reinterpret_cast<const float4*>(b + 4 * g);

  // tap-group int offsets: T = cin*576 + kd*96 + kh*16 for G = 4v+g (clamped)
  int tvi[7];
#pragma unroll
  for (int v = 0; v < 7; ++v) {
    int G = 4 * v + g;
    if (G > 26) G = 26;
    int cin = G / 9, r = G % 9;
    tvi[v] = cin * 576 + (r / 3) * 96 + (r % 3) * 16;
  }

  // position bases: P = dd*192 + dh*32 + wp (halves);
  // pbi = ((P&~3)>>1) + 1736*(P&3)  (copy select is linear in P&3)
  int pbi[7];
#pragma unroll
  for (int tl = 0; tl < 7; ++tl) {
    int rem = tl * 16;
    int dh0 = rem / 28, rem28 = rem % 28;
    int bump = (rem28 + l15) >= 28 ? 1 : 0;
    int P = dd * 192 + (dh0 + bump) * 32 + (rem28 + l15 - 28 * bump);
    pbi[tl] = ((P & ~3) >> 1) + 1736 * (P & 3);
  }

  // ---- stage copy0: 864 int-pairs (u -> halves 4u..4u+3) ----
  const float* xb = x + ((size_t)n * 3 * 16 * 32 * 32)
                  + (size_t)(4 * pd) * 1024 + (size_t)(4 * ph) * 32;
  for (int u = tid; u < 864; u += 256) {
    int r = u >> 3, c4 = (u & 7) * 4;
    int lh = r % 6, t2 = r / 6, ld = t2 % 6, cin = t2 / 6;
    float4 v4 = *reinterpret_cast<const float4*>(
        &xb[((cin * 16 + ld) * 32 + lh) * 32 + c4]);
    __half2 h01 = __float22half2_rn(make_float2(v4.x, v4.y));
    __half2 h23 = __float22half2_rn(make_float2(v4.z, v4.w));
    int2 o;
    o.x = *reinterpret_cast<int*>(&h01);
    o.y = *reinterpret_cast<int*>(&h23);
    *reinterpret_cast<int2*>(&lds[2 * u]) = o;
  }
  __syncthreads();

  // ---- build copies 1..3 (shift 1,2,3 halves). chunk = 8 ints/thread.
  //      reads lds[1728,1729] (unwritten slack, in-bounds); the garbage only
  //      lands in tail ints that are provably never read (max Q+3 = 3454). ----
  if (tid < 216) {
    int i0 = 8 * tid;
    int4 A = *reinterpret_cast<const int4*>(&lds[i0]);
    int4 B = *reinterpret_cast<const int4*>(&lds[i0 + 4]);
    int2 C = *reinterpret_cast<const int2*>(&lds[i0 + 8]);
    int c0[10] = {A.x, A.y, A.z, A.w, B.x, B.y, B.z, B.w, C.x, C.y};
    int a[9];
#pragma unroll
    for (int i = 0; i < 9; ++i)
      a[i] = (int)(((unsigned)c0[i] >> 16) | ((unsigned)c0[i + 1] << 16));
    int4 w0; w0.x = a[0]; w0.y = a[1]; w0.z = a[2]; w0.w = a[3];
    int4 w1; w1.x = a[4]; w1.y = a[5]; w1.z = a[6]; w1.w = a[7];
    *reinterpret_cast<int4*>(&lds[1736 + i0])     = w0;
    *reinterpret_cast<int4*>(&lds[1736 + i0 + 4]) = w1;
    int4 w2; w2.x = c0[1]; w2.y = c0[2]; w2.z = c0[3]; w2.w = c0[4];
    int4 w3; w3.x = c0[5]; w3.y = c0[6]; w3.z = c0[7]; w3.w = c0[8];
    *reinterpret_cast<int4*>(&lds[3472 + i0])     = w2;
    *reinterpret_cast<int4*>(&lds[3472 + i0 + 4]) = w3;
    int4 w4; w4.x = a[1]; w4.y = a[2]; w4.z = a[3]; w4.w = a[4];
    int4 w5; w5.x = a[5]; w5.y = a[6]; w5.z = a[7]; w5.w = a[8];
    *reinterpret_cast<int4*>(&lds[5208 + i0])     = w4;
    *reinterpret_cast<int4*>(&lds[5208 + i0 + 4]) = w5;
  }
  __syncthreads();

  // acc init with bias (row = channel = 4g+q)
  f32x4 acc[7];
  f32x4 binit;
  binit[0] = b4.x; binit[1] = b4.y; binit[2] = b4.z; binit[3] = b4.w;
#pragma unroll
  for (int tl = 0; tl < 7; ++tl) acc[tl] = binit;

  // ---- main: 7 K-windows x 7 N-tiles, double-buffered pipeline.
  //      Load window v+1's 7 frags while window v's 7 MFMAs execute. ----
  H4 bfA[7], bfB[7];
#pragma unroll
  for (int tl = 0; tl < 7; ++tl)
    bfA[tl].i = *reinterpret_cast<const int2*>(&lds[pbi[tl] + tvi[0]]);

#pragma unroll
  for (int vv = 0; vv < 3; ++vv) {
    const int v0 = 2 * vv, v1 = 2 * vv + 1, v2 = 2 * vv + 2;
#pragma unroll
    for (int tl = 0; tl < 7; ++tl)
      bfB[tl].i = *reinterpret_cast<const int2*>(&lds[pbi[tl] + tvi[v1]]);
#pragma unroll
    for (int tl = 0; tl < 7; ++tl)
      acc[tl] = __builtin_amdgcn_mfma_f32_16x16x16f16(wa[v0].h, bfA[tl].h, acc[tl], 0, 0, 0);
#pragma unroll
    for (int tl = 0; tl < 7; ++tl)
      bfA[tl].i = *reinterpret_cast<const int2*>(&lds[pbi[tl] + tvi[v2]]);
#pragma unroll
    for (int tl = 0; tl < 7; ++tl)
      acc[tl] = __builtin_amdgcn_mfma_f32_16x16x16f16(wa[v1].h, bfB[tl].h, acc[tl], 0, 0, 0);
  }
#pragma unroll
  for (int tl = 0; tl < 7; ++tl)
    acc[tl] = __builtin_amdgcn_mfma_f32_16x16x16f16(wa[6].h, bfA[tl].h, acc[tl], 0, 0, 0);

  // ---- epilogue: softmax over channels (cross lane-group), pool ----
  __syncthreads();      // all LDS tile reads done; reuse lds as pool buffer
  float* pool2 = reinterpret_cast<float*>(lds);   // [dd*4+dh][pw][c]

#pragma unroll
  for (int tl = 0; tl < 7; ++tl) {
    float e[4];
#pragma unroll
    for (int q = 0; q < 4; ++q) e[q] = __expf(acc[tl][q]);
    float s = (e[0] + e[1]) + (e[2] + e[3]);
    s += __shfl_xor(s, 16, 64);
    s += __shfl_xor(s, 32, 64);
    float rs = __builtin_amdgcn_rcpf(s);
    float pm[4];
#pragma unroll
    for (int q = 0; q < 4; ++q) pm[q] = e[q] * rs;
    // wp-quad reduce (l15 quads are exact wp quads; quads never straddle dh)
#pragma unroll
    for (int q = 0; q < 4; ++q) {
      pm[q] = fmaxf(pm[q], __shfl_xor(pm[q], 1, 64));
      pm[q] = fmaxf(pm[q], __shfl_xor(pm[q], 2, 64));
    }
    if ((l15 & 3) == 0) {
      int rem = tl * 16;
      int dh0 = rem / 28, rem28 = rem % 28;
      int bump = (rem28 + l15) >= 28 ? 1 : 0;
      int dh = dh0 + bump;
      int pw = (rem28 + l15 - 28 * bump) >> 2;
      float4 val = {pm[0], pm[1], pm[2], pm[3]};
      *reinterpret_cast<float4*>(&pool2[(((dd * 4 + dh) * 7 + pw) << 4) + 4 * g]) = val;
    }
  }
  __syncthreads();

  if (tid < 112) {
    int c = tid / 7, pw = tid % 7;
    float m = pool2[(pw << 4) + c];
#pragma unroll
    for (int s2 = 1; s2 < 16; ++s2)
      m = fmaxf(m, pool2[((s2 * 7 + pw) << 4) + c]);
    out[(((size_t)n * 16 + c) * 3 + pd) * 49 + (size_t)ph * 7 + pw] = m;
  }
}

extern "C" void kernel_launch(void* const* d_in, const int* in_sizes, int n_in,
                              void* d_out, int out_size, void* d_ws, size_t ws_size,
                              hipStream_t stream) {
  const float* x = (const float*)d_in[0];
  const float* w = (const float*)d_in[1];
  const float* b = (const float*)d_in[2];
  float* out = (float*)d_out;
  int2* wsA = (int2*)d_ws;   // 7 windows * 64 lanes * 8 B = 3584 B
  (void)in_sizes; (void)n_in; (void)out_size; (void)ws_size;
  hipLaunchKernelGGL(wtrans, dim3(1), dim3(448), 0, stream, w, wsA);
  hipLaunchKernelGGL(conv_sm_pool, dim3(512 * 3 * 7), dim3(256), 0, stream,
                     x, wsA, b, out);
}

// Round 4
// 183.959 us; speedup vs baseline: 1.3022x; 1.0839x over previous
//
#include <hip/hip_runtime.h>
#include <hip/hip_fp16.h>

// Fused Conv3d(3->16, 3x3x3, VALID) + bias + channel softmax + maxpool(4,4,4)/4.
// x: [512,3,16,32,32] f32, w: [16,3,3,3,3] f32, b: [16] f32 -> out [512,16,3,7,7] f32
//
// R14: R13's pipeline was silently re-collapsed by the scheduler (VGPR stayed
// 44). This round:
//  (a) sched_barrier(0) fences pin the 7-load / 7-MFMA double-buffer clusters.
//  (b) 2 LDS shift-copies (shift 0,1) instead of 4; ds_read2_b32 handles odd
//      int indices: copy = Q&1, index = Q>>1. LDS 28160 -> 13888 B;
//      __launch_bounds__(256,5) -> 5 blocks/CU.
//  (c) copy1 built in-register during staging (v_alignbit on fresh halves +
//      one extra float/thread) -- shift pass and its barrier deleted.
//  (d) loop-free staging: 216 threads, one (row,seg) each; index math once.
//  (e) DPP quad_perm (VALU-only) replaces the 8 per-tile ds_swizzle quad-max
//      shuffles; tail reduce parallelized x2 with a DPP pair-max.

typedef _Float16 half4 __attribute__((ext_vector_type(4)));
typedef float f32x4 __attribute__((ext_vector_type(4)));
union H4 { int2 i; half4 h; };

template <int CTRL>
__device__ __forceinline__ float dpp_max(float x) {
  int xi = __builtin_bit_cast(int, x);
  int yi = __builtin_amdgcn_update_dpp(xi, xi, CTRL, 0xf, 0xf, false);
  return fmaxf(x, __builtin_bit_cast(float, yi));
}
// quad_perm ctrls: xor1 = [1,0,3,2] = 0xB1, xor2 = [2,3,0,1] = 0x4E

// Frag-ready weights for K=16: wsA[v][lane] = 4 halves A[c=lane&15][k=16v+4g+j],
// tap G = 4v+g, kw = j; zero for G>=27 or kw==3.
__global__ void wtrans(const float* __restrict__ w, int2* __restrict__ wsA) {
  int t = threadIdx.x;            // 448 threads: v = t>>6, lane = t&63
  if (t >= 448) return;
  int v = t >> 6, l = t & 63;
  int c = l & 15, g = l >> 4;
  int G = 4 * v + g;
  unsigned hh[4];
  for (int j = 0; j < 4; ++j) {
    float val = (G < 27 && j < 3) ? w[c * 81 + G * 3 + j] : 0.0f;
    __half h = __float2half(val);
    hh[j] = (unsigned)__half_as_ushort(h);
  }
  int2 o;
  o.x = (int)(hh[0] | (hh[1] << 16));
  o.y = (int)(hh[2] | (hh[3] << 16));
  wsA[v * 64 + l] = o;
}

__global__ __launch_bounds__(256, 5) void conv_sm_pool(
    const float* __restrict__ x, const int2* __restrict__ wsA,
    const float* __restrict__ b, float* __restrict__ out) {
  // 2 shifted copies of the 3456-half tile stream (copy1 = shift-1-half),
  // copy stride 1736 ints. Rows unpadded: row (cin,ld,lh) = 32 halves = 16 ints.
  // Gather: half-window Q..Q+3 -> copy Q&1, int index Q>>1 (+1) via read2_b32.
  // After the main loop, reused as pool buffer [dd*4+dh][pw][c].
  __shared__ int lds[3472];

  const int tid = threadIdx.x;
  const int blk = blockIdx.x;
  const int n = blk / 21, rr = blk % 21, pd = rr / 7, ph = rr % 7;

  const int lane = tid & 63;
  const int dd = tid >> 6;            // wave = one dd slice (0..3)
  const int l15 = lane & 15, g = lane >> 4;

  // ---- setup hoisted above staging: global loads + index math ----
  H4 wa[7];
#pragma unroll
  for (int v = 0; v < 7; ++v) wa[v].i = wsA[v * 64 + lane];

  float4 b4 = *reinterpret_cast<const float4*>(b + 4 * g);

  // tap-group int offsets: T = cin*576 + kd*96 + kh*16 for G = 4v+g (clamped)
  int tvi[7];
#pragma unroll
  for (int v = 0; v < 7; ++v) {
    int G = 4 * v + g;
    if (G > 26) G = 26;
    int cin = G / 9, r = G % 9;
    tvi[v] = cin * 576 + (r / 3) * 96 + (r % 3) * 16;
  }

  // position bases: P = dd*192 + dh*32 + wp (halves);
  // pbi = (P>>1) + 1736*(P&1)
  int pbi[7];
#pragma unroll
  for (int tl = 0; tl < 7; ++tl) {
    int rem = tl * 16;
    int dh0 = rem / 28, rem28 = rem % 28;
    int bump = (rem28 + l15) >= 28 ? 1 : 0;
    int P = dd * 192 + (dh0 + bump) * 32 + (rem28 + l15 - 28 * bump);
    pbi[tl] = (P >> 1) + (P & 1) * 1736;
  }

  // ---- stage both copies, loop-free: 216 threads, one (row,seg) each.
  //      16 floats -> 8 packed ints (copy0) + 8 alignbit-shifted ints (copy1,
  //      needs 1 extra float; always in-bounds: ld<=5+? stays <16, lh+1<=30). ----
  const float* xb = x + ((size_t)n * 3 * 16 * 32 * 32)
                  + (size_t)(4 * pd) * 1024 + (size_t)(4 * ph) * 32;
  if (tid < 216) {
    int row = tid >> 1, seg = tid & 1;      // row = cin*36 + ld*6 + lh
    int lh = row % 6, t2 = row / 6, ld = t2 % 6, cin = t2 / 6;
    const float* src = &xb[((cin * 16 + ld) * 32 + lh) * 32 + seg * 16];
    float4 f0 = *reinterpret_cast<const float4*>(src);
    float4 f1 = *reinterpret_cast<const float4*>(src + 4);
    float4 f2 = *reinterpret_cast<const float4*>(src + 8);
    float4 f3 = *reinterpret_cast<const float4*>(src + 12);
    float ex = src[16];
    int c[8];
    __half2 h;
    h = __float22half2_rn(make_float2(f0.x, f0.y)); c[0] = *reinterpret_cast<int*>(&h);
    h = __float22half2_rn(make_float2(f0.z, f0.w)); c[1] = *reinterpret_cast<int*>(&h);
    h = __float22half2_rn(make_float2(f1.x, f1.y)); c[2] = *reinterpret_cast<int*>(&h);
    h = __float22half2_rn(make_float2(f1.z, f1.w)); c[3] = *reinterpret_cast<int*>(&h);
    h = __float22half2_rn(make_float2(f2.x, f2.y)); c[4] = *reinterpret_cast<int*>(&h);
    h = __float22half2_rn(make_float2(f2.z, f2.w)); c[5] = *reinterpret_cast<int*>(&h);
    h = __float22half2_rn(make_float2(f3.x, f3.y)); c[6] = *reinterpret_cast<int*>(&h);
    h = __float22half2_rn(make_float2(f3.z, f3.w)); c[7] = *reinterpret_cast<int*>(&h);
    int eh = (int)__half_as_ushort(__float2half(ex));
    int s[8];
#pragma unroll
    for (int k = 0; k < 7; ++k) s[k] = __builtin_amdgcn_alignbit(c[k + 1], c[k], 16);
    s[7] = __builtin_amdgcn_alignbit(eh, c[7], 16);
    int li = row * 16 + seg * 8;
    int4 w0; w0.x = c[0]; w0.y = c[1]; w0.z = c[2]; w0.w = c[3];
    int4 w1; w1.x = c[4]; w1.y = c[5]; w1.z = c[6]; w1.w = c[7];
    *reinterpret_cast<int4*>(&lds[li])     = w0;
    *reinterpret_cast<int4*>(&lds[li + 4]) = w1;
    int4 w2; w2.x = s[0]; w2.y = s[1]; w2.z = s[2]; w2.w = s[3];
    int4 w3; w3.x = s[4]; w3.y = s[5]; w3.z = s[6]; w3.w = s[7];
    *reinterpret_cast<int4*>(&lds[1736 + li])     = w2;
    *reinterpret_cast<int4*>(&lds[1736 + li + 4]) = w3;
  }
  __syncthreads();

  // acc init with bias (row = channel = 4g+q)
  f32x4 acc[7];
  f32x4 binit;
  binit[0] = b4.x; binit[1] = b4.y; binit[2] = b4.z; binit[3] = b4.w;
#pragma unroll
  for (int tl = 0; tl < 7; ++tl) acc[tl] = binit;

  // ---- main: 7 K-windows x 7 N-tiles, double-buffered, fence-pinned ----
  H4 bfA[7], bfB[7];
#pragma unroll
  for (int tl = 0; tl < 7; ++tl) {
    const int* p = &lds[pbi[tl] + tvi[0]];
    bfA[tl].i.x = p[0]; bfA[tl].i.y = p[1];
  }
  __builtin_amdgcn_sched_barrier(0);
#pragma unroll
  for (int vv = 0; vv < 3; ++vv) {
    const int v0 = 2 * vv, v1 = 2 * vv + 1, v2 = 2 * vv + 2;
#pragma unroll
    for (int tl = 0; tl < 7; ++tl) {
      const int* p = &lds[pbi[tl] + tvi[v1]];
      bfB[tl].i.x = p[0]; bfB[tl].i.y = p[1];
    }
    __builtin_amdgcn_sched_barrier(0);
#pragma unroll
    for (int tl = 0; tl < 7; ++tl)
      acc[tl] = __builtin_amdgcn_mfma_f32_16x16x16f16(wa[v0].h, bfA[tl].h, acc[tl], 0, 0, 0);
    __builtin_amdgcn_sched_barrier(0);
#pragma unroll
    for (int tl = 0; tl < 7; ++tl) {
      const int* p = &lds[pbi[tl] + tvi[v2]];
      bfA[tl].i.x = p[0]; bfA[tl].i.y = p[1];
    }
    __builtin_amdgcn_sched_barrier(0);
#pragma unroll
    for (int tl = 0; tl < 7; ++tl)
      acc[tl] = __builtin_amdgcn_mfma_f32_16x16x16f16(wa[v1].h, bfB[tl].h, acc[tl], 0, 0, 0);
    __builtin_amdgcn_sched_barrier(0);
  }
#pragma unroll
  for (int tl = 0; tl < 7; ++tl)
    acc[tl] = __builtin_amdgcn_mfma_f32_16x16x16f16(wa[6].h, bfA[tl].h, acc[tl], 0, 0, 0);

  // ---- epilogue: softmax over channels (cross lane-group), pool ----
  __syncthreads();      // all LDS tile reads done; reuse lds as pool buffer
  float* pool2 = reinterpret_cast<float*>(lds);   // [dd*4+dh][pw][c]

#pragma unroll
  for (int tl = 0; tl < 7; ++tl) {
    float e[4];
#pragma unroll
    for (int q = 0; q < 4; ++q) e[q] = __expf(acc[tl][q]);
    float s = (e[0] + e[1]) + (e[2] + e[3]);
    s += __shfl_xor(s, 16, 64);
    s += __shfl_xor(s, 32, 64);
    float rs = __builtin_amdgcn_rcpf(s);
    float pm[4];
#pragma unroll
    for (int q = 0; q < 4; ++q) pm[q] = e[q] * rs;
    // wp-quad max via DPP quad_perm (VALU-only; l15 quads are exact wp quads)
#pragma unroll
    for (int q = 0; q < 4; ++q) {
      pm[q] = dpp_max<0xB1>(pm[q]);   // xor1
      pm[q] = dpp_max<0x4E>(pm[q]);   // xor2
    }
    if ((l15 & 3) == 0) {
      int rem = tl * 16;
      int dh0 = rem / 28, rem28 = rem % 28;
      int bump = (rem28 + l15) >= 28 ? 1 : 0;
      int dh = dh0 + bump;
      int pw = (rem28 + l15 - 28 * bump) >> 2;
      float4 val = {pm[0], pm[1], pm[2], pm[3]};
      *reinterpret_cast<float4*>(&pool2[(((dd * 4 + dh) * 7 + pw) << 4) + 4 * g]) = val;
    }
  }
  __syncthreads();

  // tail: 224 threads, pair (tid, tid^1) split the 16 slots 8/8, DPP pair-max
  if (tid < 224) {
    int idx = tid >> 1, h = tid & 1;
    int c = idx / 7, pw = idx % 7;
    float m = pool2[(((h * 8) * 7 + pw) << 4) + c];
#pragma unroll
    for (int s2 = 1; s2 < 8; ++s2)
      m = fmaxf(m, pool2[(((h * 8 + s2) * 7 + pw) << 4) + c]);
    m = dpp_max<0xB1>(m);   // combine with partner (lanes 2k,2k+1)
    if (h == 0)
      out[(((size_t)n * 16 + c) * 3 + pd) * 49 + (size_t)ph * 7 + pw] = m;
  }
}

extern "C" void kernel_launch(void* const* d_in, const int* in_sizes, int n_in,
                              void* d_out, int out_size, void* d_ws, size_t ws_size,
                              hipStream_t stream) {
  const float* x = (const float*)d_in[0];
  const float* w = (const float*)d_in[1];
  const float* b = (const float*)d_in[2];
  float* out = (float*)d_out;
  int2* wsA = (int2*)d_ws;   // 7 windows * 64 lanes * 8 B = 3584 B
  (void)in_sizes; (void)n_in; (void)out_size; (void)ws_size;
  hipLaunchKernelGGL(wtrans, dim3(1), dim3(448), 0, stream, w, wsA);
  hipLaunchKernelGGL(conv_sm_pool, dim3(512 * 3 * 7), dim3(256), 0, stream,
                     x, wsA, b, out);
}